// Round 1
// baseline (347.935 us; speedup 1.0000x reference)
//
#include <hip/hip_runtime.h>

#define TSEQ 2048
#define CDIM 1024
#define NH 16
#define DH 64
#define NB 4

typedef __bf16 bf16x8 __attribute__((ext_vector_type(8)));
typedef float f32x4 __attribute__((ext_vector_type(4)));

static __device__ __forceinline__ ushort f2bf(float f) {
  unsigned u = __float_as_uint(f);
  unsigned r = u + 0x7fffu + ((u >> 16) & 1u);
  return (ushort)(r >> 16);
}

// global(16B, per-lane addr) -> LDS (wave-uniform base, HW adds lane*16)
static __device__ __forceinline__ void gload_lds16(const void* g, void* ldsbase) {
  __builtin_amdgcn_global_load_lds((const __attribute__((address_space(1))) void*)g,
                                   (__attribute__((address_space(3))) void*)ldsbase,
                                   16, 0, 0);
}

__global__ void cvt_x_kernel(const float4* __restrict__ src, ushort4* __restrict__ dst, int n4) {
  int i = blockIdx.x * blockDim.x + threadIdx.x;
  if (i >= n4) return;
  float4 f = src[i];
  ushort4 o;
  o.x = f2bf(f.x); o.y = f2bf(f.y); o.z = f2bf(f.z); o.w = f2bf(f.w);
  dst[i] = o;
}

// src [z][R][C] f32 -> dst [z][C][R] bf16
__global__ void transpose_cvt_kernel(const float* __restrict__ src, ushort* __restrict__ dst,
                                     int R, int Cc) {
  __shared__ float tile[32][33];
  const float* s = src + (size_t)blockIdx.z * R * Cc;
  ushort* d = dst + (size_t)blockIdx.z * R * Cc;
  int c0 = blockIdx.x * 32, r0 = blockIdx.y * 32;
  int tx = threadIdx.x, ty = threadIdx.y;
  for (int i = ty; i < 32; i += 8) {
    int r = r0 + i, c = c0 + tx;
    tile[i][tx] = (r < R && c < Cc) ? s[(size_t)r * Cc + c] : 0.f;
  }
  __syncthreads();
  for (int i = ty; i < 32; i += 8) {
    int c = c0 + i, r = r0 + tx;
    if (c < Cc && r < R) d[(size_t)c * R + r] = f2bf(tile[tx][i]);
  }
}

// QKV GEMM: per (t-tile 128, bh, sel): out[tile][64] = x[tile][1024] @ W[h][1024][64]
// A_lds [128][64] bf16 swizzled, B_lds [64(d)][64(k)] bf16 swizzled
__global__ __launch_bounds__(256) void qkv_kernel(
    const ushort* __restrict__ xb, const ushort* __restrict__ wqT,
    const ushort* __restrict__ wkT, const ushort* __restrict__ wvT,
    ushort* __restrict__ qb, ushort* __restrict__ kb, ushort* __restrict__ vTb) {
  __shared__ ushort lds[12288]; // A: 8192 elems @byte 0, B: 4096 elems @byte 16384
  const int tt = blockIdx.x, bh = blockIdx.y, sel = blockIdx.z;
  const int h = bh & (NH - 1);
  const int tid = threadIdx.x, w = tid >> 6, l = tid & 63;
  const ushort* A = xb + ((size_t)(bh >> 4) * TSEQ + (size_t)tt * 128) * CDIM;
  const ushort* Bw = (sel == 0 ? wqT : sel == 1 ? wkT : wvT) + (size_t)h * DH * CDIM;
  const int srow = l >> 3;
  const int scol = (((l & 7) ^ srow) << 3); // inverse-swizzled source column (elems)
  char* ldsb = (char*)lds;

  f32x4 acc[2][4] = {};

  for (int k0 = 0; k0 < CDIM; k0 += 64) {
#pragma unroll
    for (int i = 0; i < 6; ++i) {
      int ch = w * 6 + i;
      if (ch < 16) {
        int row = ch * 8 + srow;
        gload_lds16(A + (size_t)row * CDIM + k0 + scol, ldsb + ch * 1024);
      } else {
        int row = (ch - 16) * 8 + srow;
        gload_lds16(Bw + (size_t)row * CDIM + k0 + scol, ldsb + 16384 + (ch - 16) * 1024);
      }
    }
    __syncthreads();
#pragma unroll
    for (int ks = 0; ks < 2; ++ks) {
      bf16x8 af[2];
#pragma unroll
      for (int fm = 0; fm < 2; ++fm) {
        int row = w * 32 + fm * 16 + (l & 15);
        int cb = (ks * 64 + 16 * (l >> 4)) ^ ((row & 7) << 4);
        af[fm] = *(const bf16x8*)(ldsb + row * 128 + cb);
      }
#pragma unroll
      for (int fn = 0; fn < 4; ++fn) {
        int n = fn * 16 + (l & 15);
        int cb = (ks * 64 + 16 * (l >> 4)) ^ ((n & 7) << 4);
        bf16x8 bfr = *(const bf16x8*)(ldsb + 16384 + n * 128 + cb);
#pragma unroll
        for (int fm = 0; fm < 2; ++fm)
          acc[fm][fn] = __builtin_amdgcn_mfma_f32_16x16x32_bf16(af[fm], bfr, acc[fm][fn], 0, 0, 0);
      }
    }
    __syncthreads();
  }

  const int tbase0 = tt * 128 + w * 32;
#pragma unroll
  for (int fm = 0; fm < 2; ++fm) {
#pragma unroll
    for (int fn = 0; fn < 4; ++fn) {
      int d = fn * 16 + (l & 15);
      int tb = tbase0 + fm * 16 + (l >> 4) * 4;
      if (sel == 2) {
        ushort4 pk;
        pk.x = f2bf(acc[fm][fn][0]); pk.y = f2bf(acc[fm][fn][1]);
        pk.z = f2bf(acc[fm][fn][2]); pk.w = f2bf(acc[fm][fn][3]);
        *(ushort4*)(vTb + ((size_t)bh * DH + d) * TSEQ + tb) = pk;
      } else {
        ushort* dst = (sel == 0 ? qb : kb);
#pragma unroll
        for (int r = 0; r < 4; ++r)
          dst[((size_t)bh * TSEQ + tb + r) * DH + d] = f2bf(acc[fm][fn][r]);
      }
    }
  }
}

// Flash attention: block = (q-tile 128, bh); 4 waves x 32 q-rows; KV tiles of 64
__global__ __launch_bounds__(256) void attn_kernel(
    const ushort* __restrict__ qb, const ushort* __restrict__ kb,
    const ushort* __restrict__ vTb, ushort* __restrict__ aob) {
  __shared__ ushort lds[4096 + 4096 + 4 * 2304]; // k, vT, p (per-wave 32x72)
  const int qt = blockIdx.x, bh = blockIdx.y;
  const int b = bh >> 4, h = bh & 15;
  const int q0 = qt * 128;
  const int tid = threadIdx.x, w = tid >> 6, l = tid & 63;
  char* ldsb = (char*)lds;
  ushort* pl = lds + 8192 + w * 2304;

  bf16x8 qf[2][2];
#pragma unroll
  for (int fm = 0; fm < 2; ++fm)
#pragma unroll
    for (int ks = 0; ks < 2; ++ks) {
      int row = q0 + w * 32 + fm * 16 + (l & 15);
      int col = ks * 32 + 8 * (l >> 4);
      qf[fm][ks] = *(const bf16x8*)(qb + ((size_t)bh * TSEQ + row) * DH + col);
    }

  float mrow[2][4], lrow[2][4];
  f32x4 o[2][4] = {};
#pragma unroll
  for (int fm = 0; fm < 2; ++fm)
#pragma unroll
    for (int r = 0; r < 4; ++r) { mrow[fm][r] = -1e30f; lrow[fm][r] = 0.f; }

  const int srow = l >> 3;
  const int scol = (((l & 7) ^ srow) << 3);
  const int ntile = (q0 + 128) >> 6;

  for (int j = 0; j < ntile; ++j) {
    const int kv0 = j * 64;
#pragma unroll
    for (int i = 0; i < 4; ++i) {
      int ch = w * 4 + i;
      if (ch < 8) {
        int row = ch * 8 + srow;
        gload_lds16(kb + ((size_t)bh * TSEQ + kv0 + row) * DH + scol, ldsb + ch * 1024);
      } else {
        int drow = (ch - 8) * 8 + srow;
        gload_lds16(vTb + ((size_t)bh * DH + drow) * TSEQ + kv0 + scol, ldsb + 8192 + (ch - 8) * 1024);
      }
    }
    __syncthreads();

    // S = q @ k^T
    f32x4 s[2][4] = {};
#pragma unroll
    for (int ks = 0; ks < 2; ++ks)
#pragma unroll
      for (int fn = 0; fn < 4; ++fn) {
        int n = fn * 16 + (l & 15);
        int cb = (ks * 64 + 16 * (l >> 4)) ^ ((n & 7) << 4);
        bf16x8 kf = *(const bf16x8*)(ldsb + n * 128 + cb);
#pragma unroll
        for (int fm = 0; fm < 2; ++fm)
          s[fm][fn] = __builtin_amdgcn_mfma_f32_16x16x32_bf16(qf[fm][ks], kf, s[fm][fn], 0, 0, 0);
      }

    // online softmax (scale = 1/sqrt(C) = 1/32)
#pragma unroll
    for (int fm = 0; fm < 2; ++fm) {
      float fac4[4];
#pragma unroll
      for (int r = 0; r < 4; ++r) {
        int trow = q0 + w * 32 + fm * 16 + (l >> 4) * 4 + r;
        float rm = -1e30f;
#pragma unroll
        for (int fn = 0; fn < 4; ++fn) {
          int col = kv0 + fn * 16 + (l & 15);
          float v = s[fm][fn][r] * 0.03125f;
          if (col > trow) v = -1e30f;
          s[fm][fn][r] = v;
          rm = fmaxf(rm, v);
        }
#pragma unroll
        for (int dd = 1; dd < 16; dd <<= 1) rm = fmaxf(rm, __shfl_xor(rm, dd));
        float mo = mrow[fm][r];
        float mn = fmaxf(mo, rm);
        float fc = __expf(mo - mn);
        mrow[fm][r] = mn;
        float rs = 0.f;
#pragma unroll
        for (int fn = 0; fn < 4; ++fn) {
          float p = __expf(s[fm][fn][r] - mn);
          s[fm][fn][r] = p;
          rs += p;
        }
#pragma unroll
        for (int dd = 1; dd < 16; dd <<= 1) rs += __shfl_xor(rs, dd);
        lrow[fm][r] = lrow[fm][r] * fc + rs;
        fac4[r] = fc;
      }
#pragma unroll
      for (int fn = 0; fn < 4; ++fn)
#pragma unroll
        for (int r = 0; r < 4; ++r)
          o[fm][fn][r] *= fac4[r];
      // P -> LDS (per-wave buffer, padded stride 72 elems)
#pragma unroll
      for (int fn = 0; fn < 4; ++fn)
#pragma unroll
        for (int r = 0; r < 4; ++r)
          pl[(fm * 16 + (l >> 4) * 4 + r) * 72 + fn * 16 + (l & 15)] = f2bf(s[fm][fn][r]);
    }

    // O += P @ V
#pragma unroll
    for (int ks = 0; ks < 2; ++ks) {
      bf16x8 pf[2];
#pragma unroll
      for (int fm = 0; fm < 2; ++fm)
        pf[fm] = *(const bf16x8*)((char*)pl + (fm * 16 + (l & 15)) * 144 + ks * 64 + 16 * (l >> 4));
#pragma unroll
      for (int fn = 0; fn < 4; ++fn) {
        int n = fn * 16 + (l & 15);
        int cb = (ks * 64 + 16 * (l >> 4)) ^ ((n & 7) << 4);
        bf16x8 vf = *(const bf16x8*)(ldsb + 8192 + n * 128 + cb);
#pragma unroll
        for (int fm = 0; fm < 2; ++fm)
          o[fm][fn] = __builtin_amdgcn_mfma_f32_16x16x32_bf16(pf[fm], vf, o[fm][fn], 0, 0, 0);
      }
    }
    __syncthreads();
  }

#pragma unroll
  for (int fm = 0; fm < 2; ++fm)
#pragma unroll
    for (int fn = 0; fn < 4; ++fn) {
      int d = fn * 16 + (l & 15);
#pragma unroll
      for (int r = 0; r < 4; ++r) {
        int t = q0 + w * 32 + fm * 16 + (l >> 4) * 4 + r;
        float val = o[fm][fn][r] / lrow[fm][r];
        aob[((size_t)b * TSEQ + t) * (NH * DH) + h * DH + d] = f2bf(val);
      }
    }
}

// Projection: out[8192][1024] = ao[8192][1024] @ Wp[1024][1024] + bp, f32 out
__global__ __launch_bounds__(256) void proj_kernel(
    const ushort* __restrict__ aob, const ushort* __restrict__ wpT,
    const float* __restrict__ bp, float* __restrict__ out) {
  __shared__ ushort lds[12288];
  const int mt = blockIdx.x, nt = blockIdx.y;
  const int tid = threadIdx.x, w = tid >> 6, l = tid & 63;
  const ushort* A = aob + (size_t)mt * 128 * CDIM;
  const ushort* Bw = wpT + (size_t)nt * 64 * CDIM;
  const int srow = l >> 3;
  const int scol = (((l & 7) ^ srow) << 3);
  char* ldsb = (char*)lds;
  f32x4 acc[2][4] = {};

  for (int k0 = 0; k0 < CDIM; k0 += 64) {
#pragma unroll
    for (int i = 0; i < 6; ++i) {
      int ch = w * 6 + i;
      if (ch < 16) {
        int row = ch * 8 + srow;
        gload_lds16(A + (size_t)row * CDIM + k0 + scol, ldsb + ch * 1024);
      } else {
        int row = (ch - 16) * 8 + srow;
        gload_lds16(Bw + (size_t)row * CDIM + k0 + scol, ldsb + 16384 + (ch - 16) * 1024);
      }
    }
    __syncthreads();
#pragma unroll
    for (int ks = 0; ks < 2; ++ks) {
      bf16x8 af[2];
#pragma unroll
      for (int fm = 0; fm < 2; ++fm) {
        int row = w * 32 + fm * 16 + (l & 15);
        int cb = (ks * 64 + 16 * (l >> 4)) ^ ((row & 7) << 4);
        af[fm] = *(const bf16x8*)(ldsb + row * 128 + cb);
      }
#pragma unroll
      for (int fn = 0; fn < 4; ++fn) {
        int n = fn * 16 + (l & 15);
        int cb = (ks * 64 + 16 * (l >> 4)) ^ ((n & 7) << 4);
        bf16x8 bfr = *(const bf16x8*)(ldsb + 16384 + n * 128 + cb);
#pragma unroll
        for (int fm = 0; fm < 2; ++fm)
          acc[fm][fn] = __builtin_amdgcn_mfma_f32_16x16x32_bf16(af[fm], bfr, acc[fm][fn], 0, 0, 0);
      }
    }
    __syncthreads();
  }

#pragma unroll
  for (int fm = 0; fm < 2; ++fm)
#pragma unroll
    for (int fn = 0; fn < 4; ++fn) {
      int colg = nt * 64 + fn * 16 + (l & 15);
      float bias = bp[colg];
#pragma unroll
      for (int r = 0; r < 4; ++r) {
        int row = mt * 128 + w * 32 + fm * 16 + (l >> 4) * 4 + r;
        out[(size_t)row * CDIM + colg] = acc[fm][fn][r] + bias;
      }
    }
}

extern "C" void kernel_launch(void* const* d_in, const int* in_sizes, int n_in,
                              void* d_out, int out_size, void* d_ws, size_t ws_size,
                              hipStream_t stream) {
  (void)in_sizes; (void)n_in; (void)out_size; (void)ws_size;
  const float* x  = (const float*)d_in[0];
  const float* Wq = (const float*)d_in[1];
  const float* Wk = (const float*)d_in[2];
  const float* Wv = (const float*)d_in[3];
  const float* Wp = (const float*)d_in[4];
  const float* bp = (const float*)d_in[5];
  float* out = (float*)d_out;
  char* ws = (char*)d_ws;

  ushort* xb  = (ushort*)(ws);                      // [8192][1024] bf16
  ushort* wqT = (ushort*)(ws + (16ull << 20));      // [16][64][1024]
  ushort* wkT = (ushort*)(ws + (18ull << 20));
  ushort* wvT = (ushort*)(ws + (20ull << 20));
  ushort* wpT = (ushort*)(ws + (22ull << 20));      // [1024][1024]
  ushort* qb  = (ushort*)(ws + (24ull << 20));      // [64][2048][64]
  ushort* kb  = (ushort*)(ws + (40ull << 20));      // [64][2048][64]
  ushort* vTb = (ushort*)(ws + (56ull << 20));      // [64][64][2048]
  ushort* aob = (ushort*)(ws + (72ull << 20));      // [8192][1024]

  cvt_x_kernel<<<(NB * TSEQ * CDIM / 4 + 255) / 256, 256, 0, stream>>>(
      (const float4*)x, (ushort4*)xb, NB * TSEQ * CDIM / 4);
  transpose_cvt_kernel<<<dim3(2, 32, 16), dim3(32, 8), 0, stream>>>(Wq, wqT, CDIM, DH);
  transpose_cvt_kernel<<<dim3(2, 32, 16), dim3(32, 8), 0, stream>>>(Wk, wkT, CDIM, DH);
  transpose_cvt_kernel<<<dim3(2, 32, 16), dim3(32, 8), 0, stream>>>(Wv, wvT, CDIM, DH);
  transpose_cvt_kernel<<<dim3(32, 32, 1), dim3(32, 8), 0, stream>>>(Wp, wpT, CDIM, CDIM);

  qkv_kernel<<<dim3(16, 64, 3), 256, 0, stream>>>(xb, wqT, wkT, wvT, qb, kb, vTb);
  attn_kernel<<<dim3(16, 64), 256, 0, stream>>>(qb, kb, vTb, aob);
  proj_kernel<<<dim3(64, 16), 256, 0, stream>>>(aob, wpT, bp, out);
}

// Round 2
// 241.499 us; speedup vs baseline: 1.4407x; 1.4407x over previous
//
#include <hip/hip_runtime.h>

#define TSEQ 2048
#define CDIM 1024
#define NH 16
#define DH 64
#define NB 4

typedef __bf16 bf16x8 __attribute__((ext_vector_type(8)));
typedef float f32x4 __attribute__((ext_vector_type(4)));

// 1/sqrt(C) * log2(e): folded into Q so softmax runs in exp2 domain
#define QSCALE 0.04508422f

static __device__ __forceinline__ ushort f2bf(float f) {
  unsigned u = __float_as_uint(f);
  unsigned r = u + 0x7fffu + ((u >> 16) & 1u);
  return (ushort)(r >> 16);
}

// global(16B, per-lane addr) -> LDS (wave-uniform base, HW adds lane*16)
static __device__ __forceinline__ void gload_lds16(const void* g, void* ldsbase) {
  __builtin_amdgcn_global_load_lds((const __attribute__((address_space(1))) void*)g,
                                   (__attribute__((address_space(3))) void*)ldsbase,
                                   16, 0, 0);
}

__global__ void cvt_x_kernel(const float4* __restrict__ src, ushort4* __restrict__ dst, int n4) {
  int i = blockIdx.x * blockDim.x + threadIdx.x;
  if (i >= n4) return;
  float4 f = src[i];
  ushort4 o;
  o.x = f2bf(f.x); o.y = f2bf(f.y); o.z = f2bf(f.z); o.w = f2bf(f.w);
  dst[i] = o;
}

// src [z][R][C] f32 -> dst [z][C][R] bf16
__global__ void transpose_cvt_kernel(const float* __restrict__ src, ushort* __restrict__ dst,
                                     int R, int Cc) {
  __shared__ float tile[32][33];
  const float* s = src + (size_t)blockIdx.z * R * Cc;
  ushort* d = dst + (size_t)blockIdx.z * R * Cc;
  int c0 = blockIdx.x * 32, r0 = blockIdx.y * 32;
  int tx = threadIdx.x, ty = threadIdx.y;
  for (int i = ty; i < 32; i += 8) {
    int r = r0 + i, c = c0 + tx;
    tile[i][tx] = (r < R && c < Cc) ? s[(size_t)r * Cc + c] : 0.f;
  }
  __syncthreads();
  for (int i = ty; i < 32; i += 8) {
    int c = c0 + i, r = r0 + tx;
    if (c < Cc && r < R) d[(size_t)c * R + r] = f2bf(tile[tx][i]);
  }
}

// QKV GEMM: per (t-tile 128, bh, sel): out[tile][64] = x[tile][1024] @ W[h][1024][64]
__global__ __launch_bounds__(256) void qkv_kernel(
    const ushort* __restrict__ xb, const ushort* __restrict__ wqT,
    const ushort* __restrict__ wkT, const ushort* __restrict__ wvT,
    ushort* __restrict__ qb, ushort* __restrict__ kb, ushort* __restrict__ vTb) {
  __shared__ ushort lds[12288]; // A: 16KB @0, B: 8KB @16384
  const int tt = blockIdx.x, bh = blockIdx.y, sel = blockIdx.z;
  const int h = bh & (NH - 1);
  const int tid = threadIdx.x, w = tid >> 6, l = tid & 63;
  const ushort* A = xb + ((size_t)(bh >> 4) * TSEQ + (size_t)tt * 128) * CDIM;
  const ushort* Bw = (sel == 0 ? wqT : sel == 1 ? wkT : wvT) + (size_t)h * DH * CDIM;
  const int srow = l >> 3;
  const int scol = (((l & 7) ^ srow) << 3);
  char* ldsb = (char*)lds;

  f32x4 acc[2][4] = {};

  for (int k0 = 0; k0 < CDIM; k0 += 64) {
#pragma unroll
    for (int i = 0; i < 6; ++i) {
      int ch = w * 6 + i;
      if (ch < 16) {
        int row = ch * 8 + srow;
        gload_lds16(A + (size_t)row * CDIM + k0 + scol, ldsb + ch * 1024);
      } else {
        int row = (ch - 16) * 8 + srow;
        gload_lds16(Bw + (size_t)row * CDIM + k0 + scol, ldsb + 16384 + (ch - 16) * 1024);
      }
    }
    __syncthreads();
#pragma unroll
    for (int ks = 0; ks < 2; ++ks) {
      bf16x8 af[2];
#pragma unroll
      for (int fm = 0; fm < 2; ++fm) {
        int row = w * 32 + fm * 16 + (l & 15);
        int cb = (ks * 64 + 16 * (l >> 4)) ^ ((row & 7) << 4);
        af[fm] = *(const bf16x8*)(ldsb + row * 128 + cb);
      }
#pragma unroll
      for (int fn = 0; fn < 4; ++fn) {
        int n = fn * 16 + (l & 15);
        int cb = (ks * 64 + 16 * (l >> 4)) ^ ((n & 7) << 4);
        bf16x8 bfr = *(const bf16x8*)(ldsb + 16384 + n * 128 + cb);
#pragma unroll
        for (int fm = 0; fm < 2; ++fm)
          acc[fm][fn] = __builtin_amdgcn_mfma_f32_16x16x32_bf16(af[fm], bfr, acc[fm][fn], 0, 0, 0);
      }
    }
    __syncthreads();
  }

  const int tbase0 = tt * 128 + w * 32;
#pragma unroll
  for (int fm = 0; fm < 2; ++fm) {
#pragma unroll
    for (int fn = 0; fn < 4; ++fn) {
      int d = fn * 16 + (l & 15);
      int tb = tbase0 + fm * 16 + (l >> 4) * 4;
      if (sel == 2) {
        ushort4 pk;
        pk.x = f2bf(acc[fm][fn][0]); pk.y = f2bf(acc[fm][fn][1]);
        pk.z = f2bf(acc[fm][fn][2]); pk.w = f2bf(acc[fm][fn][3]);
        *(ushort4*)(vTb + ((size_t)bh * DH + d) * TSEQ + tb) = pk;
      } else if (sel == 0) {
        // pre-scale Q by 1/sqrt(C)*log2(e) so attention softmax is pure exp2
#pragma unroll
        for (int r = 0; r < 4; ++r)
          qb[((size_t)bh * TSEQ + tb + r) * DH + d] = f2bf(acc[fm][fn][r] * QSCALE);
      } else {
#pragma unroll
        for (int r = 0; r < 4; ++r)
          kb[((size_t)bh * TSEQ + tb + r) * DH + d] = f2bf(acc[fm][fn][r]);
      }
    }
  }
}

// Flash attention, causal-balanced: 1024 blocks, block = (pair, bh) with XCD-aware decode.
// QBLK=64 (4 waves x 16 rows), KVBLK=64, double-buffered K/V via global_load_lds.
__global__ __launch_bounds__(256) void attn_kernel(
    const ushort* __restrict__ qb, const ushort* __restrict__ kb,
    const ushort* __restrict__ vTb, ushort* __restrict__ aob) {
  __shared__ ushort lds[20992]; // bytes: K dbuf 16384, V dbuf 16384, P 9216
  char* ldsb = (char*)lds;
  const int tid = threadIdx.x, w = tid >> 6, l = tid & 63;
  const int id = blockIdx.x;
  // XCD-aware: same XCD (id&7) gets a contiguous bh range -> K/V L2 locality
  const int bh = (id & 7) * 8 + ((id >> 3) & 7);
  const int pr = id >> 6;
  const int b = bh >> 4, h = bh & 15;
  const int srow = l >> 3;
  const int scol = (((l & 7) ^ srow) << 3);
  char* pw = ldsb + 32768 + w * 2304; // per-wave P: 16 rows x 72 elems (144B stride)

#pragma unroll 1
  for (int pass = 0; pass < 2; ++pass) {
    const int qt = pass ? (31 - pr) : pr;  // paired tiles: equal total work
    const int q0 = qt * 64;
    const int nt = qt + 1;

    bf16x8 qf[2];
    {
      const ushort* qrow = qb + ((size_t)bh * TSEQ + q0 + w * 16 + (l & 15)) * DH;
      qf[0] = *(const bf16x8*)(qrow + 8 * (l >> 4));
      qf[1] = *(const bf16x8*)(qrow + 32 + 8 * (l >> 4));
    }

    float mrow[4], lrow[4];
    f32x4 o[4] = {};
#pragma unroll
    for (int r = 0; r < 4; ++r) { mrow[r] = -1e30f; lrow[r] = 0.f; }

    // prologue: tile 0 -> buf 0
#pragma unroll
    for (int i = 0; i < 4; ++i) {
      int ch = w * 4 + i;
      if (ch < 8)
        gload_lds16(kb + ((size_t)bh * TSEQ + ch * 8 + srow) * DH + scol, ldsb + ch * 1024);
      else {
        int d = (ch - 8) * 8 + srow;
        gload_lds16(vTb + ((size_t)bh * DH + d) * TSEQ + scol, ldsb + 16384 + (ch - 8) * 1024);
      }
    }

#pragma unroll 1
    for (int j = 0; j < nt; ++j) {
      __syncthreads(); // tile j resident; buf[(j+1)&1] free (compute j-1 done)
      const int cbuf = j & 1;
      if (j + 1 < nt) { // prefetch j+1; its latency hides under compute of j
        const int kv0 = (j + 1) * 64, nb = (j + 1) & 1;
#pragma unroll
        for (int i = 0; i < 4; ++i) {
          int ch = w * 4 + i;
          if (ch < 8)
            gload_lds16(kb + ((size_t)bh * TSEQ + kv0 + ch * 8 + srow) * DH + scol,
                        ldsb + nb * 8192 + ch * 1024);
          else {
            int d = (ch - 8) * 8 + srow;
            gload_lds16(vTb + ((size_t)bh * DH + d) * TSEQ + kv0 + scol,
                        ldsb + 16384 + nb * 8192 + (ch - 8) * 1024);
          }
        }
      }
      char* Kb = ldsb + cbuf * 8192;
      char* Vb = ldsb + 16384 + cbuf * 8192;

      // S = q @ k^T (already in log2 domain via prescaled Q)
      f32x4 s[4] = {};
#pragma unroll
      for (int ks = 0; ks < 2; ++ks)
#pragma unroll
        for (int fn = 0; fn < 4; ++fn) {
          int n = fn * 16 + (l & 15);
          int cbb = (ks * 64 + 16 * (l >> 4)) ^ ((n & 7) << 4);
          bf16x8 kf = *(const bf16x8*)(Kb + n * 128 + cbb);
          s[fn] = __builtin_amdgcn_mfma_f32_16x16x32_bf16(qf[ks], kf, s[fn], 0, 0, 0);
        }

      if (j == nt - 1) { // only the diagonal tile needs the causal mask
#pragma unroll
        for (int fn = 0; fn < 4; ++fn)
#pragma unroll
          for (int r = 0; r < 4; ++r) {
            int colloc = fn * 16 + (l & 15);
            int rowloc = w * 16 + (l >> 4) * 4 + r;
            if (colloc > rowloc) s[fn][r] = -1e30f;
          }
      }

      float rm4[4];
#pragma unroll
      for (int r = 0; r < 4; ++r) {
        float rm = fmaxf(fmaxf(s[0][r], s[1][r]), fmaxf(s[2][r], s[3][r]));
#pragma unroll
        for (int dd = 1; dd < 16; dd <<= 1) rm = fmaxf(rm, __shfl_xor(rm, dd));
        rm4[r] = rm;
      }
      float grow = fmaxf(fmaxf(rm4[0] - mrow[0], rm4[1] - mrow[1]),
                         fmaxf(rm4[2] - mrow[2], rm4[3] - mrow[3]));
      if (__any(grow > 8.f)) { // defer-max: P bounded by 2^8, O/l cancel the factor
        float fac[4];
#pragma unroll
        for (int r = 0; r < 4; ++r) {
          float mn = fmaxf(mrow[r], rm4[r]);
          float fc = __builtin_amdgcn_exp2f(mrow[r] - mn);
          mrow[r] = mn; lrow[r] *= fc; fac[r] = fc;
        }
#pragma unroll
        for (int fn = 0; fn < 4; ++fn)
#pragma unroll
          for (int r = 0; r < 4; ++r) o[fn][r] *= fac[r];
      }
#pragma unroll
      for (int r = 0; r < 4; ++r) {
        float rs = 0.f;
#pragma unroll
        for (int fn = 0; fn < 4; ++fn) {
          float p = __builtin_amdgcn_exp2f(s[fn][r] - mrow[r]);
          s[fn][r] = p; rs += p;
        }
#pragma unroll
        for (int dd = 1; dd < 16; dd <<= 1) rs += __shfl_xor(rs, dd);
        lrow[r] += rs;
      }
      // P -> LDS, truncating bf16 (P>=0; cheaper than RNE, error ~2^-9 rel)
#pragma unroll
      for (int fn = 0; fn < 4; ++fn)
#pragma unroll
        for (int r = 0; r < 4; ++r) {
          ushort pb = (ushort)(__float_as_uint(s[fn][r]) >> 16);
          *(ushort*)(pw + ((l >> 4) * 4 + r) * 144 + (fn * 16 + (l & 15)) * 2) = pb;
        }
      // O += P @ V
#pragma unroll
      for (int ks = 0; ks < 2; ++ks) {
        bf16x8 pf = *(const bf16x8*)(pw + (l & 15) * 144 + ks * 64 + 16 * (l >> 4));
#pragma unroll
        for (int fn = 0; fn < 4; ++fn) {
          int n = fn * 16 + (l & 15);
          int cbb = (ks * 64 + 16 * (l >> 4)) ^ ((n & 7) << 4);
          bf16x8 vf = *(const bf16x8*)(Vb + n * 128 + cbb);
          o[fn] = __builtin_amdgcn_mfma_f32_16x16x32_bf16(pf, vf, o[fn], 0, 0, 0);
        }
      }
    }

#pragma unroll
    for (int r = 0; r < 4; ++r) {
      float inv = 1.f / lrow[r];
      int t = q0 + w * 16 + (l >> 4) * 4 + r;
#pragma unroll
      for (int fn = 0; fn < 4; ++fn) {
        int d = fn * 16 + (l & 15);
        aob[((size_t)b * TSEQ + t) * (NH * DH) + h * DH + d] = f2bf(o[fn][r] * inv);
      }
    }
    __syncthreads(); // buffers must be idle before next pass's prologue loads
  }
}

// Projection: out[8192][1024] = ao[8192][1024] @ Wp[1024][1024] + bp, f32 out
__global__ __launch_bounds__(256) void proj_kernel(
    const ushort* __restrict__ aob, const ushort* __restrict__ wpT,
    const float* __restrict__ bp, float* __restrict__ out) {
  __shared__ ushort lds[12288];
  const int mt = blockIdx.x, nt = blockIdx.y;
  const int tid = threadIdx.x, w = tid >> 6, l = tid & 63;
  const ushort* A = aob + (size_t)mt * 128 * CDIM;
  const ushort* Bw = wpT + (size_t)nt * 64 * CDIM;
  const int srow = l >> 3;
  const int scol = (((l & 7) ^ srow) << 3);
  char* ldsb = (char*)lds;
  f32x4 acc[2][4] = {};

  for (int k0 = 0; k0 < CDIM; k0 += 64) {
#pragma unroll
    for (int i = 0; i < 6; ++i) {
      int ch = w * 6 + i;
      if (ch < 16) {
        int row = ch * 8 + srow;
        gload_lds16(A + (size_t)row * CDIM + k0 + scol, ldsb + ch * 1024);
      } else {
        int row = (ch - 16) * 8 + srow;
        gload_lds16(Bw + (size_t)row * CDIM + k0 + scol, ldsb + 16384 + (ch - 16) * 1024);
      }
    }
    __syncthreads();
#pragma unroll
    for (int ks = 0; ks < 2; ++ks) {
      bf16x8 af[2];
#pragma unroll
      for (int fm = 0; fm < 2; ++fm) {
        int row = w * 32 + fm * 16 + (l & 15);
        int cb = (ks * 64 + 16 * (l >> 4)) ^ ((row & 7) << 4);
        af[fm] = *(const bf16x8*)(ldsb + row * 128 + cb);
      }
#pragma unroll
      for (int fn = 0; fn < 4; ++fn) {
        int n = fn * 16 + (l & 15);
        int cb = (ks * 64 + 16 * (l >> 4)) ^ ((n & 7) << 4);
        bf16x8 bfr = *(const bf16x8*)(ldsb + 16384 + n * 128 + cb);
#pragma unroll
        for (int fm = 0; fm < 2; ++fm)
          acc[fm][fn] = __builtin_amdgcn_mfma_f32_16x16x32_bf16(af[fm], bfr, acc[fm][fn], 0, 0, 0);
      }
    }
    __syncthreads();
  }

#pragma unroll
  for (int fm = 0; fm < 2; ++fm)
#pragma unroll
    for (int fn = 0; fn < 4; ++fn) {
      int colg = nt * 64 + fn * 16 + (l & 15);
      float bias = bp[colg];
#pragma unroll
      for (int r = 0; r < 4; ++r) {
        int row = mt * 128 + w * 32 + fm * 16 + (l >> 4) * 4 + r;
        out[(size_t)row * CDIM + colg] = acc[fm][fn][r] + bias;
      }
    }
}

extern "C" void kernel_launch(void* const* d_in, const int* in_sizes, int n_in,
                              void* d_out, int out_size, void* d_ws, size_t ws_size,
                              hipStream_t stream) {
  (void)in_sizes; (void)n_in; (void)out_size; (void)ws_size;
  const float* x  = (const float*)d_in[0];
  const float* Wq = (const float*)d_in[1];
  const float* Wk = (const float*)d_in[2];
  const float* Wv = (const float*)d_in[3];
  const float* Wp = (const float*)d_in[4];
  const float* bp = (const float*)d_in[5];
  float* out = (float*)d_out;
  char* ws = (char*)d_ws;

  ushort* xb  = (ushort*)(ws);                      // [8192][1024] bf16
  ushort* wqT = (ushort*)(ws + (16ull << 20));      // [16][64][1024]
  ushort* wkT = (ushort*)(ws + (18ull << 20));
  ushort* wvT = (ushort*)(ws + (20ull << 20));
  ushort* wpT = (ushort*)(ws + (22ull << 20));      // [1024][1024]
  ushort* qb  = (ushort*)(ws + (24ull << 20));      // [64][2048][64] (pre-scaled)
  ushort* kb  = (ushort*)(ws + (40ull << 20));      // [64][2048][64]
  ushort* vTb = (ushort*)(ws + (56ull << 20));      // [64][64][2048]
  ushort* aob = (ushort*)(ws + (72ull << 20));      // [8192][1024]

  cvt_x_kernel<<<(NB * TSEQ * CDIM / 4 + 255) / 256, 256, 0, stream>>>(
      (const float4*)x, (ushort4*)xb, NB * TSEQ * CDIM / 4);
  transpose_cvt_kernel<<<dim3(2, 32, 16), dim3(32, 8), 0, stream>>>(Wq, wqT, CDIM, DH);
  transpose_cvt_kernel<<<dim3(2, 32, 16), dim3(32, 8), 0, stream>>>(Wk, wkT, CDIM, DH);
  transpose_cvt_kernel<<<dim3(2, 32, 16), dim3(32, 8), 0, stream>>>(Wv, wvT, CDIM, DH);
  transpose_cvt_kernel<<<dim3(32, 32, 1), dim3(32, 8), 0, stream>>>(Wp, wpT, CDIM, CDIM);

  qkv_kernel<<<dim3(16, 64, 3), 256, 0, stream>>>(xb, wqT, wkT, wvT, qb, kb, vTb);
  attn_kernel<<<dim3(1024), 256, 0, stream>>>(qb, kb, vTb, aob);
  proj_kernel<<<dim3(64, 16), 256, 0, stream>>>(aob, wpT, bp, out);
}

// Round 3
// 202.198 us; speedup vs baseline: 1.7208x; 1.1944x over previous
//
#include <hip/hip_runtime.h>

#define TSEQ 2048
#define CDIM 1024
#define NH 16
#define DH 64
#define NB 4

typedef __bf16 bf16x8 __attribute__((ext_vector_type(8)));
typedef float f32x4 __attribute__((ext_vector_type(4)));

// 1/sqrt(C) * log2(e): folded into Q so softmax runs in exp2 domain
#define QSCALE 0.04508422f

static __device__ __forceinline__ ushort f2bf(float f) {
  unsigned u = __float_as_uint(f);
  unsigned r = u + 0x7fffu + ((u >> 16) & 1u);
  return (ushort)(r >> 16);
}

// global(16B, per-lane addr) -> LDS (wave-uniform base, HW adds lane*16)
static __device__ __forceinline__ void gload_lds16(const void* g, void* ldsbase) {
  __builtin_amdgcn_global_load_lds((const __attribute__((address_space(1))) void*)g,
                                   (__attribute__((address_space(3))) void*)ldsbase,
                                   16, 0, 0);
}

__global__ void cvt_x_kernel(const float4* __restrict__ src, ushort4* __restrict__ dst, int n4) {
  int i = blockIdx.x * blockDim.x + threadIdx.x;
  if (i >= n4) return;
  float4 f = src[i];
  ushort4 o;
  o.x = f2bf(f.x); o.y = f2bf(f.y); o.z = f2bf(f.z); o.w = f2bf(f.w);
  dst[i] = o;
}

// src [z][R][C] f32 -> dst [z][C][R] bf16
__global__ void transpose_cvt_kernel(const float* __restrict__ src, ushort* __restrict__ dst,
                                     int R, int Cc) {
  __shared__ float tile[32][33];
  const float* s = src + (size_t)blockIdx.z * R * Cc;
  ushort* d = dst + (size_t)blockIdx.z * R * Cc;
  int c0 = blockIdx.x * 32, r0 = blockIdx.y * 32;
  int tx = threadIdx.x, ty = threadIdx.y;
  for (int i = ty; i < 32; i += 8) {
    int r = r0 + i, c = c0 + tx;
    tile[i][tx] = (r < R && c < Cc) ? s[(size_t)r * Cc + c] : 0.f;
  }
  __syncthreads();
  for (int i = ty; i < 32; i += 8) {
    int c = c0 + i, r = r0 + tx;
    if (c < Cc && r < R) d[(size_t)c * R + r] = f2bf(tile[tx][i]);
  }
}

// QKV GEMM: per (t-tile 128, bh, sel): out[tile][64] = x[tile][1024] @ W[h][1024][64]
__global__ __launch_bounds__(256) void qkv_kernel(
    const ushort* __restrict__ xb, const ushort* __restrict__ wqT,
    const ushort* __restrict__ wkT, const ushort* __restrict__ wvT,
    ushort* __restrict__ qb, ushort* __restrict__ kb, ushort* __restrict__ vTb) {
  __shared__ ushort lds[12288]; // A: 16KB @0, B: 8KB @16384
  const int tt = blockIdx.x, bh = blockIdx.y, sel = blockIdx.z;
  const int h = bh & (NH - 1);
  const int tid = threadIdx.x, w = tid >> 6, l = tid & 63;
  const ushort* A = xb + ((size_t)(bh >> 4) * TSEQ + (size_t)tt * 128) * CDIM;
  const ushort* Bw = (sel == 0 ? wqT : sel == 1 ? wkT : wvT) + (size_t)h * DH * CDIM;
  const int srow = l >> 3;
  const int scol = (((l & 7) ^ srow) << 3);
  char* ldsb = (char*)lds;

  f32x4 acc[2][4] = {};

  for (int k0 = 0; k0 < CDIM; k0 += 64) {
#pragma unroll
    for (int i = 0; i < 6; ++i) {
      int ch = w * 6 + i;
      if (ch < 16) {
        int row = ch * 8 + srow;
        gload_lds16(A + (size_t)row * CDIM + k0 + scol, ldsb + ch * 1024);
      } else {
        int row = (ch - 16) * 8 + srow;
        gload_lds16(Bw + (size_t)row * CDIM + k0 + scol, ldsb + 16384 + (ch - 16) * 1024);
      }
    }
    __syncthreads();
#pragma unroll
    for (int ks = 0; ks < 2; ++ks) {
      bf16x8 af[2];
#pragma unroll
      for (int fm = 0; fm < 2; ++fm) {
        int row = w * 32 + fm * 16 + (l & 15);
        int cb = (ks * 64 + 16 * (l >> 4)) ^ ((row & 7) << 4);
        af[fm] = *(const bf16x8*)(ldsb + row * 128 + cb);
      }
#pragma unroll
      for (int fn = 0; fn < 4; ++fn) {
        int n = fn * 16 + (l & 15);
        int cb = (ks * 64 + 16 * (l >> 4)) ^ ((n & 7) << 4);
        bf16x8 bfr = *(const bf16x8*)(ldsb + 16384 + n * 128 + cb);
#pragma unroll
        for (int fm = 0; fm < 2; ++fm)
          acc[fm][fn] = __builtin_amdgcn_mfma_f32_16x16x32_bf16(af[fm], bfr, acc[fm][fn], 0, 0, 0);
      }
    }
    __syncthreads();
  }

  const int tbase0 = tt * 128 + w * 32;
#pragma unroll
  for (int fm = 0; fm < 2; ++fm) {
#pragma unroll
    for (int fn = 0; fn < 4; ++fn) {
      int d = fn * 16 + (l & 15);
      int tb = tbase0 + fm * 16 + (l >> 4) * 4;
      if (sel == 2) {
        ushort4 pk;
        pk.x = f2bf(acc[fm][fn][0]); pk.y = f2bf(acc[fm][fn][1]);
        pk.z = f2bf(acc[fm][fn][2]); pk.w = f2bf(acc[fm][fn][3]);
        *(ushort4*)(vTb + ((size_t)bh * DH + d) * TSEQ + tb) = pk;
      } else if (sel == 0) {
        // pre-scale Q by 1/sqrt(C)*log2(e) so attention softmax is pure exp2
#pragma unroll
        for (int r = 0; r < 4; ++r)
          qb[((size_t)bh * TSEQ + tb + r) * DH + d] = f2bf(acc[fm][fn][r] * QSCALE);
      } else {
#pragma unroll
        for (int r = 0; r < 4; ++r)
          kb[((size_t)bh * TSEQ + tb + r) * DH + d] = f2bf(acc[fm][fn][r]);
      }
    }
  }
}

// Flash attention, causal-balanced: 1024 blocks, block = (pair, bh) with XCD-aware decode.
// QBLK=64 (4 waves x 16 rows), KVBLK=64, double-buffered K/V via global_load_lds.
// Swapped QK^T: S^T = mfma(K_frag, Q_frag) -> lane owns 16 k-values of one q-column
// (q = l&15), so row-softmax is in-lane VALU + 2 shfl_xor instead of 32 bpermutes.
__global__ __launch_bounds__(256) void attn_kernel(
    const ushort* __restrict__ qb, const ushort* __restrict__ kb,
    const ushort* __restrict__ vTb, ushort* __restrict__ aob) {
  __shared__ ushort lds[20992]; // bytes: K dbuf 16384, V dbuf 16384, P 9216
  char* ldsb = (char*)lds;
  const int tid = threadIdx.x, w = tid >> 6, l = tid & 63;
  const int id = blockIdx.x;
  // XCD-aware: same XCD (id&7) gets a contiguous bh range -> K/V L2 locality
  const int bh = (id & 7) * 8 + ((id >> 3) & 7);
  const int pr = id >> 6;
  const int b = bh >> 4, h = bh & 15;
  const int g = l >> 4, q = l & 15;
  const int srow = l >> 3;
  const int scol = (((l & 7) ^ srow) << 3);
  char* pw = ldsb + 32768 + w * 2304; // per-wave P: 16 rows x 72 elems (144B stride)

#pragma unroll 1
  for (int pass = 0; pass < 2; ++pass) {
    const int qt = pass ? (31 - pr) : pr;  // paired tiles: equal total work
    const int q0 = qt * 64;
    const int nt = qt + 1;

    bf16x8 qf[2];
    {
      const ushort* qrow = qb + ((size_t)bh * TSEQ + q0 + w * 16 + q) * DH;
      qf[0] = *(const bf16x8*)(qrow + 8 * g);
      qf[1] = *(const bf16x8*)(qrow + 32 + 8 * g);
    }

    float m = -1e30f, lsum = 0.f;
    f32x4 o[4] = {};

    // prologue: tile 0 -> buf 0
#pragma unroll
    for (int i = 0; i < 4; ++i) {
      int ch = w * 4 + i;
      if (ch < 8)
        gload_lds16(kb + ((size_t)bh * TSEQ + ch * 8 + srow) * DH + scol, ldsb + ch * 1024);
      else {
        int d = (ch - 8) * 8 + srow;
        gload_lds16(vTb + ((size_t)bh * DH + d) * TSEQ + scol, ldsb + 16384 + (ch - 8) * 1024);
      }
    }

#pragma unroll 1
    for (int j = 0; j < nt; ++j) {
      __syncthreads(); // tile j resident; buf[(j+1)&1] free (compute j-1 done)
      const int cbuf = j & 1;
      if (j + 1 < nt) { // prefetch j+1; its latency hides under compute of j
        const int kv0 = (j + 1) * 64, nb = (j + 1) & 1;
#pragma unroll
        for (int i = 0; i < 4; ++i) {
          int ch = w * 4 + i;
          if (ch < 8)
            gload_lds16(kb + ((size_t)bh * TSEQ + kv0 + ch * 8 + srow) * DH + scol,
                        ldsb + nb * 8192 + ch * 1024);
          else {
            int d = (ch - 8) * 8 + srow;
            gload_lds16(vTb + ((size_t)bh * DH + d) * TSEQ + kv0 + scol,
                        ldsb + 16384 + nb * 8192 + (ch - 8) * 1024);
          }
        }
      }
      char* Kb = ldsb + cbuf * 8192;
      char* Vb = ldsb + 16384 + cbuf * 8192;

      // S^T = K @ Q^T (log2 domain via prescaled Q); s[fn][r] = S[k=fn*16+4g+r][q]
      f32x4 s[4] = {};
#pragma unroll
      for (int ks = 0; ks < 2; ++ks)
#pragma unroll
        for (int fn = 0; fn < 4; ++fn) {
          int n = fn * 16 + q;
          int cbb = (ks * 64 + 16 * g) ^ ((n & 7) << 4);
          bf16x8 kf = *(const bf16x8*)(Kb + n * 128 + cbb);
          s[fn] = __builtin_amdgcn_mfma_f32_16x16x32_bf16(kf, qf[ks], s[fn], 0, 0, 0);
        }

      if (j == nt - 1) { // only the diagonal tile needs the causal mask (kv0 == q0)
#pragma unroll
        for (int fn = 0; fn < 4; ++fn)
#pragma unroll
          for (int r = 0; r < 4; ++r)
            if (fn * 16 + 4 * g + r > w * 16 + q) s[fn][r] = -1e30f;
      }

      // in-lane row max over this lane's 16 k-values, then across the 4 g-replicas
      float rm = fmaxf(fmaxf(s[0][0], s[0][1]), fmaxf(s[0][2], s[0][3]));
#pragma unroll
      for (int fn = 1; fn < 4; ++fn)
        rm = fmaxf(rm, fmaxf(fmaxf(s[fn][0], s[fn][1]), fmaxf(s[fn][2], s[fn][3])));
      rm = fmaxf(rm, __shfl_xor(rm, 16));
      rm = fmaxf(rm, __shfl_xor(rm, 32));

      if (__any(rm - m > 8.f)) { // defer-max: P bounded by 2^8, O/l cancel the factor
        float mn = fmaxf(m, rm);
        float fc = __builtin_amdgcn_exp2f(m - mn);
        m = mn; lsum *= fc;
#pragma unroll
        for (int r = 0; r < 4; ++r) {
          // o rows live at q'=4g+r; fc lives at lane with l&15==q' (any replica)
          float fcq = __shfl(fc, (l & 0x30) | (4 * g + r), 64);
#pragma unroll
          for (int fn = 0; fn < 4; ++fn) o[fn][r] *= fcq;
        }
      }

      float rs = 0.f;
#pragma unroll
      for (int fn = 0; fn < 4; ++fn) {
        float p0 = __builtin_amdgcn_exp2f(s[fn][0] - m);
        float p1 = __builtin_amdgcn_exp2f(s[fn][1] - m);
        float p2 = __builtin_amdgcn_exp2f(s[fn][2] - m);
        float p3 = __builtin_amdgcn_exp2f(s[fn][3] - m);
        rs += (p0 + p1) + (p2 + p3);
        // truncating bf16 pack (P>=0), 4 consecutive k -> one 8B LDS write (2-way = free)
        uint u0 = (__float_as_uint(p0) >> 16) | (__float_as_uint(p1) & 0xffff0000u);
        uint u1 = (__float_as_uint(p2) >> 16) | (__float_as_uint(p3) & 0xffff0000u);
        *(uint2*)(pw + q * 144 + fn * 32 + g * 8) = make_uint2(u0, u1);
      }
      rs += __shfl_xor(rs, 16);
      rs += __shfl_xor(rs, 32);
      lsum += rs;

      // O += P @ V
#pragma unroll
      for (int ks = 0; ks < 2; ++ks) {
        bf16x8 pf = *(const bf16x8*)(pw + q * 144 + ks * 64 + 16 * g);
#pragma unroll
        for (int fn = 0; fn < 4; ++fn) {
          int n = fn * 16 + q;
          int cbb = (ks * 64 + 16 * g) ^ ((n & 7) << 4);
          bf16x8 vf = *(const bf16x8*)(Vb + n * 128 + cbb);
          o[fn] = __builtin_amdgcn_mfma_f32_16x16x32_bf16(pf, vf, o[fn], 0, 0, 0);
        }
      }
    }

    float inv = 1.f / lsum; // for q-column l&15
#pragma unroll
    for (int r = 0; r < 4; ++r) {
      float invq = __shfl(inv, (l & 0x30) | (4 * g + r), 64);
      int t = q0 + w * 16 + 4 * g + r;
#pragma unroll
      for (int fn = 0; fn < 4; ++fn) {
        int d = fn * 16 + q;
        aob[((size_t)b * TSEQ + t) * (NH * DH) + h * DH + d] = f2bf(o[fn][r] * invq);
      }
    }
    __syncthreads(); // buffers must be idle before next pass's prologue loads
  }
}

// Projection: out[8192][1024] = ao[8192][1024] @ Wp[1024][1024] + bp, f32 out
__global__ __launch_bounds__(256) void proj_kernel(
    const ushort* __restrict__ aob, const ushort* __restrict__ wpT,
    const float* __restrict__ bp, float* __restrict__ out) {
  __shared__ ushort lds[12288];
  const int mt = blockIdx.x, nt = blockIdx.y;
  const int tid = threadIdx.x, w = tid >> 6, l = tid & 63;
  const ushort* A = aob + (size_t)mt * 128 * CDIM;
  const ushort* Bw = wpT + (size_t)nt * 64 * CDIM;
  const int srow = l >> 3;
  const int scol = (((l & 7) ^ srow) << 3);
  char* ldsb = (char*)lds;
  f32x4 acc[2][4] = {};

  for (int k0 = 0; k0 < CDIM; k0 += 64) {
#pragma unroll
    for (int i = 0; i < 6; ++i) {
      int ch = w * 6 + i;
      if (ch < 16) {
        int row = ch * 8 + srow;
        gload_lds16(A + (size_t)row * CDIM + k0 + scol, ldsb + ch * 1024);
      } else {
        int row = (ch - 16) * 8 + srow;
        gload_lds16(Bw + (size_t)row * CDIM + k0 + scol, ldsb + 16384 + (ch - 16) * 1024);
      }
    }
    __syncthreads();
#pragma unroll
    for (int ks = 0; ks < 2; ++ks) {
      bf16x8 af[2];
#pragma unroll
      for (int fm = 0; fm < 2; ++fm) {
        int row = w * 32 + fm * 16 + (l & 15);
        int cb = (ks * 64 + 16 * (l >> 4)) ^ ((row & 7) << 4);
        af[fm] = *(const bf16x8*)(ldsb + row * 128 + cb);
      }
#pragma unroll
      for (int fn = 0; fn < 4; ++fn) {
        int n = fn * 16 + (l & 15);
        int cb = (ks * 64 + 16 * (l >> 4)) ^ ((n & 7) << 4);
        bf16x8 bfr = *(const bf16x8*)(ldsb + 16384 + n * 128 + cb);
#pragma unroll
        for (int fm = 0; fm < 2; ++fm)
          acc[fm][fn] = __builtin_amdgcn_mfma_f32_16x16x32_bf16(af[fm], bfr, acc[fm][fn], 0, 0, 0);
      }
    }
    __syncthreads();
  }

#pragma unroll
  for (int fm = 0; fm < 2; ++fm)
#pragma unroll
    for (int fn = 0; fn < 4; ++fn) {
      int colg = nt * 64 + fn * 16 + (l & 15);
      float bias = bp[colg];
#pragma unroll
      for (int r = 0; r < 4; ++r) {
        int row = mt * 128 + w * 32 + fm * 16 + (l >> 4) * 4 + r;
        out[(size_t)row * CDIM + colg] = acc[fm][fn][r] + bias;
      }
    }
}

extern "C" void kernel_launch(void* const* d_in, const int* in_sizes, int n_in,
                              void* d_out, int out_size, void* d_ws, size_t ws_size,
                              hipStream_t stream) {
  (void)in_sizes; (void)n_in; (void)out_size; (void)ws_size;
  const float* x  = (const float*)d_in[0];
  const float* Wq = (const float*)d_in[1];
  const float* Wk = (const float*)d_in[2];
  const float* Wv = (const float*)d_in[3];
  const float* Wp = (const float*)d_in[4];
  const float* bp = (const float*)d_in[5];
  float* out = (float*)d_out;
  char* ws = (char*)d_ws;

  ushort* xb  = (ushort*)(ws);                      // [8192][1024] bf16
  ushort* wqT = (ushort*)(ws + (16ull << 20));      // [16][64][1024]
  ushort* wkT = (ushort*)(ws + (18ull << 20));
  ushort* wvT = (ushort*)(ws + (20ull << 20));
  ushort* wpT = (ushort*)(ws + (22ull << 20));      // [1024][1024]
  ushort* qb  = (ushort*)(ws + (24ull << 20));      // [64][2048][64] (pre-scaled)
  ushort* kb  = (ushort*)(ws + (40ull << 20));      // [64][2048][64]
  ushort* vTb = (ushort*)(ws + (56ull << 20));      // [64][64][2048]
  ushort* aob = (ushort*)(ws + (72ull << 20));      // [8192][1024]

  cvt_x_kernel<<<(NB * TSEQ * CDIM / 4 + 255) / 256, 256, 0, stream>>>(
      (const float4*)x, (ushort4*)xb, NB * TSEQ * CDIM / 4);
  transpose_cvt_kernel<<<dim3(2, 32, 16), dim3(32, 8), 0, stream>>>(Wq, wqT, CDIM, DH);
  transpose_cvt_kernel<<<dim3(2, 32, 16), dim3(32, 8), 0, stream>>>(Wk, wkT, CDIM, DH);
  transpose_cvt_kernel<<<dim3(2, 32, 16), dim3(32, 8), 0, stream>>>(Wv, wvT, CDIM, DH);
  transpose_cvt_kernel<<<dim3(32, 32, 1), dim3(32, 8), 0, stream>>>(Wp, wpT, CDIM, CDIM);

  qkv_kernel<<<dim3(16, 64, 3), 256, 0, stream>>>(xb, wqT, wkT, wvT, qb, kb, vTb);
  attn_kernel<<<dim3(1024), 256, 0, stream>>>(qb, kb, vTb, aob);
  proj_kernel<<<dim3(64, 16), 256, 0, stream>>>(aob, wpT, bp, out);
}